// Round 5
// baseline (239.870 us; speedup 1.0000x reference)
//
#include <hip/hip_runtime.h>
#include <stdint.h>

typedef short s16x8 __attribute__((ext_vector_type(8)));
typedef float f32x4 __attribute__((ext_vector_type(4)));

__device__ __forceinline__ float bits2f(unsigned short u) {
    union { unsigned int i; float f; } c; c.i = ((unsigned int)u) << 16; return c.f;
}
__device__ __forceinline__ unsigned short f2bits(float f) {
    union { float f; unsigned int i; } c; c.f = f;
    unsigned int x = c.i;
    unsigned int r = (x + 0x7FFFu + ((x >> 16) & 1u)) >> 16;
    return (unsigned short)r;
}
__device__ __forceinline__ unsigned int pack2(float a, float b) {
    return (unsigned int)f2bits(a) | ((unsigned int)f2bits(b) << 16);
}

// ---------------------------------------------------------------------------
// f32 -> bf16 bulk convert; n8 = n/8
__global__ __launch_bounds__(256) void k_cvt(
    const float* __restrict__ src, unsigned short* __restrict__ dst, int n8)
{
    int i = blockIdx.x * 256 + threadIdx.x;
    if (i >= n8) return;
    const float* s = src + (size_t)i * 8;
    float4 a = *(const float4*)s, b = *(const float4*)(s + 4);
    unsigned int q[4] = { pack2(a.x, a.y), pack2(a.z, a.w), pack2(b.x, b.y), pack2(b.z, b.w) };
    *(s16x8*)(dst + (size_t)i * 8) = *(s16x8*)q;
}

// ---------------------------------------------------------------------------
// transpose (WqT only, 256x256 bf16): dst[dr][c] = src[c][dr]
__global__ __launch_bounds__(256) void k_transpose(
    const unsigned short* __restrict__ src, unsigned short* __restrict__ dst,
    int RS, int DS)
{
    int dr = blockIdx.x * 256 + threadIdx.x;
    int c0 = blockIdx.y * 8;
    __align__(16) unsigned short tmp[8];
#pragma unroll
    for (int j = 0; j < 8; ++j) tmp[j] = src[(size_t)(c0 + j) * RS + dr];
    *(s16x8*)(dst + (size_t)dr * DS + c0) = *(s16x8*)tmp;
}

// ---------------------------------------------------------------------------
// gemm_wide: C[m][n] = sum_k A[m][k]*B[k][n]; M=K=256 fixed, N=4096, BM=256,
// BN=64. A bf16 (lda=256). B: f32 (BBF16=0) or bf16 (=1), ldb=4096.
// XCVT=1: write the converted bf16 B-tile to xbout (same layout as B).
// EPI==0: C bf16. EPI==1: C f32 = gamma[m]*(acc+bias[m]) + Xres[m][n].
template <int EPI, int BBF16, int XCVT>
__global__ __launch_bounds__(256) void gemm_wide(
    const unsigned short* __restrict__ A, const void* __restrict__ B,
    void* __restrict__ C, unsigned short* __restrict__ xbout,
    const float* __restrict__ Xres, const float* __restrict__ gamma,
    const float* __restrict__ bias, long Abs)
{
    __shared__ unsigned short As[256][72];
    __shared__ unsigned short Bs[64][66];
    int bz = blockIdx.z;
    int n0 = blockIdx.x * 64;
    const unsigned short* Ab = A + (size_t)bz * Abs;
    int t = threadIdx.x, w = t >> 6, l = t & 63, lm = l & 15, lq = l >> 4;
    int mw = w * 64;

    f32x4 acc[4][4];
    f32x4 zero = {0.f, 0.f, 0.f, 0.f};
#pragma unroll
    for (int i = 0; i < 4; ++i)
#pragma unroll
        for (int j = 0; j < 4; ++j) acc[i][j] = zero;

    for (int kk = 0; kk < 256; kk += 64) {
#pragma unroll
        for (int i = 0; i < 8; ++i) {
            int idx = t + i * 256;
            int r = idx >> 3, ch = idx & 7;
            *(s16x8*)&As[r][ch * 8] = *(const s16x8*)(Ab + (size_t)r * 256 + kk + ch * 8);
        }
#pragma unroll
        for (int i = 0; i < 2; ++i) {
            int idx = t + i * 256;
            int c = idx >> 3, ch = idx & 7;
            unsigned int* qp = (unsigned int*)&Bs[c][ch * 8];   // 4B aligned
            if (BBF16) {
                const unsigned short* bp = (const unsigned short*)B + (size_t)bz * 1048576
                                         + (size_t)(kk + c) * 4096 + n0 + ch * 8;
                union { s16x8 v; unsigned int u[4]; } cv;
                cv.v = *(const s16x8*)bp;
                qp[0] = cv.u[0]; qp[1] = cv.u[1]; qp[2] = cv.u[2]; qp[3] = cv.u[3];
            } else {
                const float* bp = (const float*)B + (size_t)bz * 1048576
                                + (size_t)(kk + c) * 4096 + n0 + ch * 8;
                float4 v0 = *(const float4*)bp, v1 = *(const float4*)(bp + 4);
                unsigned int q[4] = { pack2(v0.x, v0.y), pack2(v0.z, v0.w),
                                      pack2(v1.x, v1.y), pack2(v1.z, v1.w) };
                qp[0] = q[0]; qp[1] = q[1]; qp[2] = q[2]; qp[3] = q[3];
                if (XCVT) {
                    unsigned short* xp = xbout + (size_t)bz * 1048576
                                       + (size_t)(kk + c) * 4096 + n0 + ch * 8;
                    *(s16x8*)xp = *(s16x8*)q;
                }
            }
        }
        __syncthreads();
#pragma unroll
        for (int ks = 0; ks < 2; ++ks) {
            s16x8 af[4];
#pragma unroll
            for (int mi = 0; mi < 4; ++mi)
                af[mi] = *(const s16x8*)&As[mw + mi * 16 + lm][ks * 32 + lq * 8];
#pragma unroll
            for (int ni = 0; ni < 4; ++ni) {
                s16x8 bfr;
#pragma unroll
                for (int j = 0; j < 8; ++j) bfr[j] = (short)Bs[ks * 32 + lq * 8 + j][ni * 16 + lm];
#pragma unroll
                for (int mi = 0; mi < 4; ++mi)
                    acc[mi][ni] = __builtin_amdgcn_mfma_f32_16x16x32_bf16(af[mi], bfr, acc[mi][ni], 0, 0, 0);
            }
        }
        __syncthreads();
    }

#pragma unroll
    for (int mi = 0; mi < 4; ++mi)
#pragma unroll
        for (int r = 0; r < 4; ++r) {
            int m = mw + mi * 16 + lq * 4 + r;
            float g = 0.f, bo = 0.f;
            if (EPI == 1) { g = gamma[m]; bo = bias[m]; }
#pragma unroll
            for (int ni = 0; ni < 4; ++ni) {
                int n = n0 + ni * 16 + lm;
                size_t idx = (size_t)m * 4096 + n;
                float v = acc[mi][ni][r];
                if (EPI == 1) {
                    float* Cb = (float*)C + (size_t)bz * 1048576;
                    Cb[idx] = g * (v + bo) + Xres[(size_t)bz * 1048576 + idx];
                } else {
                    unsigned short* Cb = (unsigned short*)C + (size_t)bz * 1048576;
                    Cb[idx] = f2bits(v);
                }
            }
        }
}

// ---------------------------------------------------------------------------
// gemm_bt: C[m][n] = sum_k A[m][k]*Bt[n][k], both bf16 k-contiguous.
// BM=BN=128, BK=64. bz: b=bz&15, kc=bz>>4; K-origin kc*Kstep. C indexed by bz.
// AEXP==1: A elements transformed exp(a - stats[row].x) * stats[row].y
template <int AEXP>
__global__ __launch_bounds__(256) void gemm_bt(
    const unsigned short* __restrict__ A, const unsigned short* __restrict__ Bt,
    unsigned short* __restrict__ C, const float2* __restrict__ stats,
    int K, int Kstep, int lda, int ldb, int ldc,
    long Abs, long Bbs, long Cbs)
{
    __shared__ unsigned short As[128][72];
    __shared__ unsigned short Bs[128][72];
    int bz = blockIdx.z;
    int b = bz & 15, kc = bz >> 4;
    int m0 = blockIdx.y * 128, n0 = blockIdx.x * 128;
    const unsigned short* Ab = A + (size_t)b * Abs + (size_t)m0 * lda + (size_t)kc * Kstep;
    const unsigned short* Bb = Bt + (size_t)b * Bbs + (size_t)n0 * ldb + (size_t)kc * Kstep;
    int t = threadIdx.x;
    int w = t >> 6, l = t & 63, lm = l & 15, lq = l >> 4;
    int mw = (w >> 1) * 64, nw = (w & 1) * 64;

    f32x4 acc[4][4];
    f32x4 zero = {0.f, 0.f, 0.f, 0.f};
#pragma unroll
    for (int i = 0; i < 4; ++i)
#pragma unroll
        for (int j = 0; j < 4; ++j) acc[i][j] = zero;

    for (int kk = 0; kk < K; kk += 64) {
#pragma unroll
        for (int i = 0; i < 4; ++i) {
            int idx = t + i * 256;
            int r = idx >> 3, ch = idx & 7;
            s16x8 av = *(const s16x8*)(Ab + (size_t)r * lda + kk + ch * 8);
            if (AEXP) {
                float2 st = stats[b * 256 + m0 + r];
                unsigned int q[4];
#pragma unroll
                for (int j = 0; j < 4; ++j) {
                    float e0 = __expf(bits2f((unsigned short)av[2 * j]) - st.x) * st.y;
                    float e1 = __expf(bits2f((unsigned short)av[2 * j + 1]) - st.x) * st.y;
                    q[j] = pack2(e0, e1);
                }
                av = *(s16x8*)q;
            }
            *(s16x8*)&As[r][ch * 8] = av;
            *(s16x8*)&Bs[r][ch * 8] = *(const s16x8*)(Bb + (size_t)r * ldb + kk + ch * 8);
        }
        __syncthreads();
#pragma unroll
        for (int ks = 0; ks < 2; ++ks) {
            s16x8 af[4], bfr[4];
#pragma unroll
            for (int mi = 0; mi < 4; ++mi) af[mi]  = *(const s16x8*)&As[mw + mi * 16 + lm][ks * 32 + lq * 8];
#pragma unroll
            for (int ni = 0; ni < 4; ++ni) bfr[ni] = *(const s16x8*)&Bs[nw + ni * 16 + lm][ks * 32 + lq * 8];
#pragma unroll
            for (int mi = 0; mi < 4; ++mi)
#pragma unroll
                for (int ni = 0; ni < 4; ++ni)
                    acc[mi][ni] = __builtin_amdgcn_mfma_f32_16x16x32_bf16(af[mi], bfr[ni], acc[mi][ni], 0, 0, 0);
        }
        __syncthreads();
    }

    unsigned short* Cb = C + (size_t)bz * Cbs;
#pragma unroll
    for (int mi = 0; mi < 4; ++mi)
#pragma unroll
        for (int r = 0; r < 4; ++r) {
            int m = m0 + mw + mi * 16 + lq * 4 + r;
#pragma unroll
            for (int ni = 0; ni < 4; ++ni) {
                int n = n0 + nw + ni * 16 + lm;
                Cb[(size_t)m * ldc + n] = f2bits(acc[mi][ni][r]);
            }
        }
}

// ---------------------------------------------------------------------------
// row stats for softmax: stats[row] = (max, 1/sum(exp(v-max))) over 4096 cols
__global__ __launch_bounds__(256) void k_softstats(
    const unsigned short* __restrict__ kbuf, float2* __restrict__ stats)
{
    const unsigned short* p = kbuf + (size_t)blockIdx.x * 4096;
    int t = threadIdx.x;
    __shared__ float red[4];

    s16x8 r0 = *(const s16x8*)(p + t * 16);
    s16x8 r1 = *(const s16x8*)(p + t * 16 + 8);
    float v[16];
    float m = -1e30f;
#pragma unroll
    for (int i = 0; i < 8; ++i) { v[i] = bits2f((unsigned short)r0[i]); v[8 + i] = bits2f((unsigned short)r1[i]); }
#pragma unroll
    for (int i = 0; i < 16; ++i) m = fmaxf(m, v[i]);
#pragma unroll
    for (int off = 32; off >= 1; off >>= 1) m = fmaxf(m, __shfl_xor(m, off));
    if ((t & 63) == 0) red[t >> 6] = m;
    __syncthreads();
    m = fmaxf(fmaxf(red[0], red[1]), fmaxf(red[2], red[3]));
    __syncthreads();

    float s = 0.f;
#pragma unroll
    for (int i = 0; i < 16; ++i) s += __expf(v[i] - m);
#pragma unroll
    for (int off = 32; off >= 1; off >>= 1) s += __shfl_xor(s, off);
    if ((t & 63) == 0) red[t >> 6] = s;
    __syncthreads();
    if (t == 0) {
        s = red[0] + red[1] + red[2] + red[3];
        stats[blockIdx.x] = make_float2(m, 1.0f / s);
    }
}

// ---------------------------------------------------------------------------
// per (b,h): ctx[d][e] = sum_kc sum_c Gp[kc*16+b][h*64+d][c] * Wv[h*64+e][c]
// then      W2[b][o][h*64+d] = sum_e w_out[o][h*64+e] * ctx[d][e]
__global__ __launch_bounds__(256) void k_ctxw2(
    const unsigned short* __restrict__ Gp, const unsigned short* __restrict__ wb,
    const unsigned short* __restrict__ wob, unsigned short* __restrict__ W2)
{
    __shared__ unsigned short ctxs[64][72];
    int h = blockIdx.x, b = blockIdx.y;
    int t = threadIdx.x, w = t >> 6, l = t & 63, lm = l & 15, lq = l >> 4;
    const unsigned short* Wv = wb + 131072 + (size_t)(h * 64) * 256;
    f32x4 zero = {0.f, 0.f, 0.f, 0.f};

    // phase 1: wave w computes ctx d-rows [w*16, w*16+16), summing 8 kc partials
    f32x4 acc[4];
#pragma unroll
    for (int i = 0; i < 4; ++i) acc[i] = zero;
    for (int kc = 0; kc < 8; ++kc) {
        const unsigned short* Gb = Gp + (size_t)(kc * 16 + b) * 65536 + (size_t)(h * 64) * 256;
#pragma unroll
        for (int kk = 0; kk < 256; kk += 32) {
            s16x8 a = *(const s16x8*)(Gb + (size_t)(w * 16 + lm) * 256 + kk + lq * 8);
#pragma unroll
            for (int ni = 0; ni < 4; ++ni) {
                s16x8 bb = *(const s16x8*)(Wv + (size_t)(ni * 16 + lm) * 256 + kk + lq * 8);
                acc[ni] = __builtin_amdgcn_mfma_f32_16x16x32_bf16(a, bb, acc[ni], 0, 0, 0);
            }
        }
    }
#pragma unroll
    for (int ni = 0; ni < 4; ++ni)
#pragma unroll
        for (int r = 0; r < 4; ++r)
            ctxs[w * 16 + lq * 4 + r][ni * 16 + lm] = f2bits(acc[ni][r]);
    __syncthreads();

    // phase 2: wave w computes W2 o-rows [w*64, w*64+64)
    f32x4 acc2[4][4];
#pragma unroll
    for (int i = 0; i < 4; ++i)
#pragma unroll
        for (int j = 0; j < 4; ++j) acc2[i][j] = zero;
#pragma unroll
    for (int ks = 0; ks < 2; ++ks) {
        s16x8 af[4], bfr[4];
#pragma unroll
        for (int mi = 0; mi < 4; ++mi)
            af[mi] = *(const s16x8*)(wob + (size_t)(w * 64 + mi * 16 + lm) * 256 + h * 64 + ks * 32 + lq * 8);
#pragma unroll
        for (int ni = 0; ni < 4; ++ni) bfr[ni] = *(const s16x8*)&ctxs[ni * 16 + lm][ks * 32 + lq * 8];
#pragma unroll
        for (int mi = 0; mi < 4; ++mi)
#pragma unroll
            for (int ni = 0; ni < 4; ++ni)
                acc2[mi][ni] = __builtin_amdgcn_mfma_f32_16x16x32_bf16(af[mi], bfr[ni], acc2[mi][ni], 0, 0, 0);
    }
    unsigned short* W2b = W2 + (size_t)b * 65536;
#pragma unroll
    for (int mi = 0; mi < 4; ++mi)
#pragma unroll
        for (int r = 0; r < 4; ++r) {
            int o = w * 64 + mi * 16 + lq * 4 + r;
#pragma unroll
            for (int ni = 0; ni < 4; ++ni)
                W2b[(size_t)o * 256 + h * 64 + ni * 16 + lm] = f2bits(acc2[mi][ni][r]);
        }
}

// ---------------------------------------------------------------------------
extern "C" void kernel_launch(void* const* d_in, const int* in_sizes, int n_in,
                              void* d_out, int out_size, void* d_ws, size_t ws_size,
                              hipStream_t stream)
{
    (void)in_sizes; (void)n_in; (void)out_size; (void)ws_size;
    const float* x      = (const float*)d_in[0]; // [16][256][4096] f32
    const float* w_qkv  = (const float*)d_in[1]; // [768][256] f32
    const float* w_out  = (const float*)d_in[2]; // [256][256] f32
    const float* b_out  = (const float*)d_in[3]; // [256] f32
    const float* gamma  = (const float*)d_in[4]; // [256] f32
    unsigned short* kbuf = (unsigned short*)d_out; // first 32MB of d_out = bf16 k scratch
    // final output: f32, K5 overwrites the full 64MB last (stream-ordered)

    char* ws = (char*)d_ws;                                       // total ws use: ~55.2 MB
    unsigned short* xb  = (unsigned short*)(ws);                  // [16][256][4096] bf16 = 33,554,432
    unsigned short* Gp  = (unsigned short*)(ws + 33554432);       // [128][256][256] bf16 = 16,777,216
    unsigned short* W2  = (unsigned short*)(ws + 50331648);       //  2,097,152
    unsigned short* W3  = (unsigned short*)(ws + 52428800);       //  2,097,152
    unsigned short* WqT = (unsigned short*)(ws + 54525952);       //    131,072
    unsigned short* wb  = (unsigned short*)(ws + 54657024);       // w_qkv bf16: 393,216
    unsigned short* wob = (unsigned short*)(ws + 55050240);       // w_out bf16: 131,072
    float2*         st  = (float2*)        (ws + 55181312);       // [4096] row stats: 32,768

    // weight conversions + WqT
    k_cvt<<<dim3(96), 256, 0, stream>>>(w_qkv, wb, 24576);
    k_cvt<<<dim3(32), 256, 0, stream>>>(w_out, wob, 8192);
    k_transpose<<<dim3(1, 32, 1), 256, 0, stream>>>(wb, WqT, 256, 256);

    // K1: k = Wk @ x -> kbuf (bf16), fused x->xb conversion  (BM=256,BN=64)
    gemm_wide<0, 0, 1><<<dim3(64, 1, 16), 256, 0, stream>>>(
        wb + 65536, x, kbuf, xb, nullptr, nullptr, nullptr, 0L);

    // row softmax stats (max, 1/sum)
    k_softstats<<<dim3(4096), 256, 0, stream>>>(kbuf, st);

    // KG: Gp[kc*16+b] = softk_b[:, chunk] @ x_b[:, chunk]^T  (exp inline, K-split x8)
    gemm_bt<1><<<dim3(2, 2, 128), 256, 0, stream>>>(
        kbuf, xb, Gp, st, 512, 512, 4096, 4096, 256,
        1048576L, 1048576L, 65536L);

    // ctx (sum of 8 Gp partials in f32) + W2, fused per (b,h)
    k_ctxw2<<<dim3(4, 16), 256, 0, stream>>>(Gp, wb, wob, W2);

    // W3[b] = W2[b] @ Wq
    gemm_bt<0><<<dim3(2, 2, 16), 256, 0, stream>>>(
        W2, WqT, W3, nullptr, 256, 0, 256, 256, 256,
        65536L, 0L, 65536L);

    // K5: out(f32) = gamma*(W3 @ xb + b_out) + x   (BM=256,BN=64, B=xb bf16)
    gemm_wide<1, 1, 0><<<dim3(64, 1, 16), 256, 0, stream>>>(
        W3, xb, d_out, nullptr, x, gamma, b_out, 65536L);
}

// Round 6
// 237.877 us; speedup vs baseline: 1.0084x; 1.0084x over previous
//
#include <hip/hip_runtime.h>
#include <stdint.h>

typedef short s16x8 __attribute__((ext_vector_type(8)));
typedef float f32x4 __attribute__((ext_vector_type(4)));

__device__ __forceinline__ float bits2f(unsigned short u) {
    union { unsigned int i; float f; } c; c.i = ((unsigned int)u) << 16; return c.f;
}
__device__ __forceinline__ unsigned short f2bits(float f) {
    union { float f; unsigned int i; } c; c.f = f;
    unsigned int x = c.i;
    unsigned int r = (x + 0x7FFFu + ((x >> 16) & 1u)) >> 16;
    return (unsigned short)r;
}
__device__ __forceinline__ unsigned int pack2(float a, float b) {
    return (unsigned int)f2bits(a) | ((unsigned int)f2bits(b) << 16);
}

// ---------------------------------------------------------------------------
// zero-init for softmax row sums
__global__ __launch_bounds__(256) void k_zero(float* __restrict__ p, int n)
{
    int i = blockIdx.x * 256 + threadIdx.x;
    if (i < n) p[i] = 0.f;
}

// ---------------------------------------------------------------------------
// one-shot weight prep: wb = bf16(w_qkv) [96 blks], wob = bf16(w_out) [32 blks],
// WqT[c][o] = bf16(w_qkv[o][c]) for o<256 [32 blks]
__global__ __launch_bounds__(256) void k_weights(
    const float* __restrict__ w_qkv, const float* __restrict__ w_out,
    unsigned short* __restrict__ wb, unsigned short* __restrict__ wob,
    unsigned short* __restrict__ WqT)
{
    int bid = blockIdx.x, t = threadIdx.x;
    if (bid < 96) {
        int i = bid * 256 + t;                    // 24576 threads x 8 elems
        const float* s = w_qkv + (size_t)i * 8;
        float4 a = *(const float4*)s, b = *(const float4*)(s + 4);
        unsigned int q[4] = { pack2(a.x, a.y), pack2(a.z, a.w), pack2(b.x, b.y), pack2(b.z, b.w) };
        *(s16x8*)(wb + (size_t)i * 8) = *(s16x8*)q;
    } else if (bid < 128) {
        int i = (bid - 96) * 256 + t;             // 8192 threads x 8 elems
        const float* s = w_out + (size_t)i * 8;
        float4 a = *(const float4*)s, b = *(const float4*)(s + 4);
        unsigned int q[4] = { pack2(a.x, a.y), pack2(a.z, a.w), pack2(b.x, b.y), pack2(b.z, b.w) };
        *(s16x8*)(wob + (size_t)i * 8) = *(s16x8*)q;
    } else {
        int c0 = (bid - 128) * 8;                 // hd chunk
        int dr = t;                               // c row
        __align__(16) unsigned short tmp[8];
#pragma unroll
        for (int j = 0; j < 8; ++j) tmp[j] = f2bits(w_qkv[(size_t)(c0 + j) * 256 + dr]);
        *(s16x8*)(WqT + (size_t)dr * 256 + c0) = *(s16x8*)tmp;
    }
}

// ---------------------------------------------------------------------------
// x[b][c][n] f32 -> xb[b][c][n] bf16  AND  xT[b][n][c] bf16.
// 64x64 tiles; LDS stride 65 shorts => both write rows and column gathers are
// bank-conflict-free (64 distinct (addr mod 64) residues, dword pairs broadcast).
__global__ __launch_bounds__(256) void k_xpose(
    const float* __restrict__ x, unsigned short* __restrict__ xb,
    unsigned short* __restrict__ xT)
{
    __shared__ unsigned short tile[64 * 65];
    int b = blockIdx.z, c0 = blockIdx.y * 64, n0 = blockIdx.x * 64;
    int t = threadIdx.x;
    int cr = t >> 2, nc = (t & 3) * 16;
    const float* xp = x + ((size_t)(b * 256 + c0 + cr)) * 4096 + n0 + nc;
    float4 v0 = *(const float4*)xp,       v1 = *(const float4*)(xp + 4),
           v2 = *(const float4*)(xp + 8), v3 = *(const float4*)(xp + 12);
    unsigned int q[8] = { pack2(v0.x, v0.y), pack2(v0.z, v0.w), pack2(v1.x, v1.y), pack2(v1.z, v1.w),
                          pack2(v2.x, v2.y), pack2(v2.z, v2.w), pack2(v3.x, v3.y), pack2(v3.z, v3.w) };
    unsigned short* xbp = xb + ((size_t)(b * 256 + c0 + cr)) * 4096 + n0 + nc;
    *(s16x8*)xbp = *(s16x8*)q;
    *(s16x8*)(xbp + 8) = *(s16x8*)(q + 4);
    const unsigned short* qs = (const unsigned short*)q;
#pragma unroll
    for (int i = 0; i < 16; ++i) tile[cr * 65 + nc + i] = qs[i];
    __syncthreads();
    int nr = t >> 2, cc = (t & 3) * 16;
    __align__(16) unsigned short o[16];
#pragma unroll
    for (int j = 0; j < 16; ++j) o[j] = tile[(cc + j) * 65 + nr];
    unsigned short* xtp = xT + ((size_t)(b * 4096 + n0 + nr)) * 256 + c0 + cc;
    *(s16x8*)xtp = *(s16x8*)o;
    *(s16x8*)(xtp + 8) = *(s16x8*)(o + 8);
}

// ---------------------------------------------------------------------------
// gemm_bt: C[m][n] = sum_k A[m][k]*Bt[n][k], bf16 operands, k-contiguous.
// BM=BN=128, BK=64. bz: b=bz&15, kc=bz>>4; K-origin kc*Kstep. C indexed by bz.
// AEXP: A-element -> exp(a) * (1/ssum[b*256+row])   (softmax w/o max-shift)
// EPI 0: C bf16.  EPI 1: C f32 = gamma[m]*(acc+bias[m]) + Xres[m][n].
// EPI 2: C bf16 + atomicAdd per-row sum of exp(acc) into ssum.
template <int AEXP, int EPI>
__global__ __launch_bounds__(256) void gemm_bt(
    const unsigned short* __restrict__ A, const unsigned short* __restrict__ Bt,
    void* __restrict__ C, float* __restrict__ ssum,
    int K, int Kstep, int lda, int ldb, int ldc,
    long Abs, long Bbs, long Cbs,
    const float* __restrict__ Xres, const float* __restrict__ gamma,
    const float* __restrict__ bias)
{
    __shared__ unsigned short As[128][72];
    __shared__ unsigned short Bs[128][72];
    int bz = blockIdx.z;
    int b = bz & 15, kc = bz >> 4;
    int m0 = blockIdx.y * 128, n0 = blockIdx.x * 128;
    const unsigned short* Ab = A + (size_t)b * Abs + (size_t)m0 * lda + (size_t)kc * Kstep;
    const unsigned short* Bb = Bt + (size_t)b * Bbs + (size_t)n0 * ldb + (size_t)kc * Kstep;
    int t = threadIdx.x;
    int w = t >> 6, l = t & 63, lm = l & 15, lq = l >> 4;
    int mw = (w >> 1) * 64, nw = (w & 1) * 64;

    float inva[4];
    if (AEXP) {
#pragma unroll
        for (int i = 0; i < 4; ++i) {
            int r = (t + i * 256) >> 3;
            inva[i] = 1.0f / ssum[b * 256 + m0 + r];
        }
    }

    f32x4 acc[4][4];
    f32x4 zero = {0.f, 0.f, 0.f, 0.f};
#pragma unroll
    for (int i = 0; i < 4; ++i)
#pragma unroll
        for (int j = 0; j < 4; ++j) acc[i][j] = zero;

    for (int kk = 0; kk < K; kk += 64) {
#pragma unroll
        for (int i = 0; i < 4; ++i) {
            int idx = t + i * 256;
            int r = idx >> 3, ch = idx & 7;
            s16x8 av = *(const s16x8*)(Ab + (size_t)r * lda + kk + ch * 8);
            if (AEXP) {
                unsigned int q[4];
#pragma unroll
                for (int j = 0; j < 4; ++j) {
                    float e0 = __expf(bits2f((unsigned short)av[2 * j])) * inva[i];
                    float e1 = __expf(bits2f((unsigned short)av[2 * j + 1])) * inva[i];
                    q[j] = pack2(e0, e1);
                }
                av = *(s16x8*)q;
            }
            *(s16x8*)&As[r][ch * 8] = av;
            *(s16x8*)&Bs[r][ch * 8] = *(const s16x8*)(Bb + (size_t)r * ldb + kk + ch * 8);
        }
        __syncthreads();
#pragma unroll
        for (int ks = 0; ks < 2; ++ks) {
            s16x8 af[4], bfr[4];
#pragma unroll
            for (int mi = 0; mi < 4; ++mi) af[mi]  = *(const s16x8*)&As[mw + mi * 16 + lm][ks * 32 + lq * 8];
#pragma unroll
            for (int ni = 0; ni < 4; ++ni) bfr[ni] = *(const s16x8*)&Bs[nw + ni * 16 + lm][ks * 32 + lq * 8];
#pragma unroll
            for (int mi = 0; mi < 4; ++mi)
#pragma unroll
                for (int ni = 0; ni < 4; ++ni)
                    acc[mi][ni] = __builtin_amdgcn_mfma_f32_16x16x32_bf16(af[mi], bfr[ni], acc[mi][ni], 0, 0, 0);
        }
        __syncthreads();
    }

#pragma unroll
    for (int mi = 0; mi < 4; ++mi)
#pragma unroll
        for (int r = 0; r < 4; ++r) {
            int m = m0 + mw + mi * 16 + lq * 4 + r;
            float g = 0.f, bo = 0.f;
            if (EPI == 1) { g = gamma[m]; bo = bias[m]; }
#pragma unroll
            for (int ni = 0; ni < 4; ++ni) {
                int n = n0 + nw + ni * 16 + lm;
                size_t idx = (size_t)m * ldc + n;
                float v = acc[mi][ni][r];
                if (EPI == 1) {
                    float* Cb = (float*)C + (size_t)bz * Cbs;
                    Cb[idx] = g * (v + bo) + Xres[(size_t)bz * Cbs + idx];
                } else {
                    unsigned short* Cb = (unsigned short*)C + (size_t)bz * Cbs;
                    Cb[idx] = f2bits(v);
                }
            }
            if (EPI == 2) {
                float rs = 0.f;
#pragma unroll
                for (int ni = 0; ni < 4; ++ni) rs += __expf(acc[mi][ni][r]);
#pragma unroll
                for (int off = 1; off < 16; off <<= 1) rs += __shfl_xor(rs, off);
                if (lm == 0) atomicAdd(&ssum[b * 256 + m], rs);
            }
        }
}

// ---------------------------------------------------------------------------
// per (b,h): ctx[d][e] = sum_kc sum_c Gp[kc*16+b][h*64+d][c] * Wv[h*64+e][c]
// then      W2[b][o][h*64+d] = sum_e w_out[o][h*64+e] * ctx[d][e]
__global__ __launch_bounds__(256) void k_ctxw2(
    const unsigned short* __restrict__ Gp, const unsigned short* __restrict__ wb,
    const unsigned short* __restrict__ wob, unsigned short* __restrict__ W2)
{
    __shared__ unsigned short ctxs[64][72];
    int h = blockIdx.x, b = blockIdx.y;
    int t = threadIdx.x, w = t >> 6, l = t & 63, lm = l & 15, lq = l >> 4;
    const unsigned short* Wv = wb + 131072 + (size_t)(h * 64) * 256;
    f32x4 zero = {0.f, 0.f, 0.f, 0.f};

    f32x4 acc[4];
#pragma unroll
    for (int i = 0; i < 4; ++i) acc[i] = zero;
    for (int kc = 0; kc < 8; ++kc) {
        const unsigned short* Gb = Gp + (size_t)(kc * 16 + b) * 65536 + (size_t)(h * 64) * 256;
#pragma unroll
        for (int kk = 0; kk < 256; kk += 32) {
            s16x8 a = *(const s16x8*)(Gb + (size_t)(w * 16 + lm) * 256 + kk + lq * 8);
#pragma unroll
            for (int ni = 0; ni < 4; ++ni) {
                s16x8 bb = *(const s16x8*)(Wv + (size_t)(ni * 16 + lm) * 256 + kk + lq * 8);
                acc[ni] = __builtin_amdgcn_mfma_f32_16x16x32_bf16(a, bb, acc[ni], 0, 0, 0);
            }
        }
    }
#pragma unroll
    for (int ni = 0; ni < 4; ++ni)
#pragma unroll
        for (int r = 0; r < 4; ++r)
            ctxs[w * 16 + lq * 4 + r][ni * 16 + lm] = f2bits(acc[ni][r]);
    __syncthreads();

    f32x4 acc2[4][4];
#pragma unroll
    for (int i = 0; i < 4; ++i)
#pragma unroll
        for (int j = 0; j < 4; ++j) acc2[i][j] = zero;
#pragma unroll
    for (int ks = 0; ks < 2; ++ks) {
        s16x8 af[4], bfr[4];
#pragma unroll
        for (int mi = 0; mi < 4; ++mi)
            af[mi] = *(const s16x8*)(wob + (size_t)(w * 64 + mi * 16 + lm) * 256 + h * 64 + ks * 32 + lq * 8);
#pragma unroll
        for (int ni = 0; ni < 4; ++ni) bfr[ni] = *(const s16x8*)&ctxs[ni * 16 + lm][ks * 32 + lq * 8];
#pragma unroll
        for (int mi = 0; mi < 4; ++mi)
#pragma unroll
            for (int ni = 0; ni < 4; ++ni)
                acc2[mi][ni] = __builtin_amdgcn_mfma_f32_16x16x32_bf16(af[mi], bfr[ni], acc2[mi][ni], 0, 0, 0);
    }
    unsigned short* W2b = W2 + (size_t)b * 65536;
#pragma unroll
    for (int mi = 0; mi < 4; ++mi)
#pragma unroll
        for (int r = 0; r < 4; ++r) {
            int o = w * 64 + mi * 16 + lq * 4 + r;
#pragma unroll
            for (int ni = 0; ni < 4; ++ni)
                W2b[(size_t)o * 256 + h * 64 + ni * 16 + lm] = f2bits(acc2[mi][ni][r]);
        }
}

// ---------------------------------------------------------------------------
extern "C" void kernel_launch(void* const* d_in, const int* in_sizes, int n_in,
                              void* d_out, int out_size, void* d_ws, size_t ws_size,
                              hipStream_t stream)
{
    (void)in_sizes; (void)n_in; (void)out_size; (void)ws_size;
    const float* x      = (const float*)d_in[0]; // [16][256][4096] f32
    const float* w_qkv  = (const float*)d_in[1]; // [768][256] f32
    const float* w_out  = (const float*)d_in[2]; // [256][256] f32
    const float* b_out  = (const float*)d_in[3]; // [256] f32
    const float* gamma  = (const float*)d_in[4]; // [256] f32
    unsigned short* kbuf = (unsigned short*)d_out; // first 32MB = bf16 k scratch
    // final output: f32, K5 overwrites all 64MB last (stream-ordered)

    char* ws = (char*)d_ws;                                  // total ~88.75 MB
    unsigned short* xT  = (unsigned short*)(ws);             // [16][4096][256] bf16 = 33,554,432
    unsigned short* xb  = (unsigned short*)(ws + 33554432);  // [16][256][4096] bf16 = 33,554,432
    unsigned short* Gp  = (unsigned short*)(ws + 67108864);  // [128][256][256] bf16 = 16,777,216
    unsigned short* W2  = (unsigned short*)(ws + 83886080);  //  2,097,152
    unsigned short* W3  = (unsigned short*)(ws + 85983232);  //  2,097,152
    unsigned short* WqT = (unsigned short*)(ws + 88080384);  //    131,072
    unsigned short* wb  = (unsigned short*)(ws + 88211456);  //    393,216
    unsigned short* wob = (unsigned short*)(ws + 88604672);  //    131,072
    float*          ssum = (float*)        (ws + 88735744);  // [4096] f32 = 16,384

    // 1. zero softmax row sums
    k_zero<<<dim3(16), 256, 0, stream>>>(ssum, 4096);
    // 2. weight prep (wb, wob, WqT)
    k_weights<<<dim3(160), 256, 0, stream>>>(w_qkv, w_out, wb, wob, WqT);
    // 3. x -> xb (bf16 same layout) + xT (bf16 transposed)
    k_xpose<<<dim3(64, 4, 16), 256, 0, stream>>>(x, xb, xT);

    // 4. K1: k = Wk @ x -> kbuf bf16, fused exp-rowsum atomics
    gemm_bt<0, 2><<<dim3(32, 2, 16), 256, 0, stream>>>(
        wb + 65536, xT, kbuf, ssum, 256, 0, 256, 256, 4096,
        0L, 1048576L, 1048576L, nullptr, nullptr, nullptr);

    // 5. KG: Gp[kc*16+b] = softk_b[:, chunk] @ x_b[:, chunk]^T (exp inline, K-split x8)
    gemm_bt<1, 0><<<dim3(2, 2, 128), 256, 0, stream>>>(
        kbuf, xb, Gp, ssum, 512, 512, 4096, 4096, 256,
        1048576L, 1048576L, 65536L, nullptr, nullptr, nullptr);

    // 6. ctx (f32 sum of 8 Gp partials) + W2, fused per (b,h)
    k_ctxw2<<<dim3(4, 16), 256, 0, stream>>>(Gp, wb, wob, W2);

    // 7. W3[b] = W2[b] @ Wq
    gemm_bt<0, 0><<<dim3(2, 2, 16), 256, 0, stream>>>(
        W2, WqT, W3, nullptr, 256, 0, 256, 256, 256,
        65536L, 0L, 65536L, nullptr, nullptr, nullptr);

    // 8. K5: out(f32) = gamma*(W3 @ x + b_out) + x
    gemm_bt<0, 1><<<dim3(32, 2, 16), 256, 0, stream>>>(
        W3, xT, d_out, nullptr, 256, 0, 256, 256, 4096,
        65536L, 1048576L, 1048576L, x, gamma, b_out);
}